// Round 1
// baseline (2746.005 us; speedup 1.0000x reference)
//
#include <hip/hip_runtime.h>

#define F 64

// ---------------- edge1: GINEConv message + scatter-add ----------------
// msg = relu(x_state[src] + edge_attr@We + be); agg[dst] += msg
// 16 threads per edge, float4 per thread.
__global__ __launch_bounds__(256) void edge1_kernel(
    const float* __restrict__ x_state,
    const float* __restrict__ edge_attr,
    const float* __restrict__ We,   // [2][F]
    const float* __restrict__ be,   // [F]
    const int* __restrict__ src,
    const int* __restrict__ dst,
    float* __restrict__ agg,
    int E)
{
    long long t = (long long)blockIdx.x * blockDim.x + threadIdx.x;
    int e = (int)(t >> 4);
    int q = (int)(t & 15);
    if (e >= E) return;
    int s = src[e];
    int d = dst[e];
    float2 ea = ((const float2* __restrict__)edge_attr)[e];
    float4 xs = ((const float4* __restrict__)(x_state + (size_t)s * F))[q];
    float4 w0 = ((const float4* __restrict__)We)[q];          // We[0][4q..4q+3]
    float4 w1 = ((const float4* __restrict__)(We + F))[q];    // We[1][...]
    float4 bb = ((const float4* __restrict__)be)[q];
    float m0 = fmaxf(xs.x + ea.x * w0.x + ea.y * w1.x + bb.x, 0.f);
    float m1 = fmaxf(xs.y + ea.x * w0.y + ea.y * w1.y + bb.y, 0.f);
    float m2 = fmaxf(xs.z + ea.x * w0.z + ea.y * w1.z + bb.z, 0.f);
    float m3 = fmaxf(xs.w + ea.x * w0.w + ea.y * w1.w + bb.w, 0.f);
    float* ap = agg + (size_t)d * F + q * 4;
    atomicAdd(ap + 0, m0);
    atomicAdd(ap + 1, m1);
    atomicAdd(ap + 2, m2);
    atomicAdd(ap + 3, m3);
}

// ---------------- mlp1: x1 = relu((x_task+agg)@W1a+b1a)@W1b + b1b ------
__global__ __launch_bounds__(256) void mlp1_kernel(
    const float* __restrict__ x_task,
    const float* __restrict__ agg,
    const float* __restrict__ W1a, const float* __restrict__ b1a,
    const float* __restrict__ W1b, const float* __restrict__ b1b,
    float* __restrict__ x1,
    int n)
{
    __shared__ float sWa[F * F];
    __shared__ float sWb[F * F];
    __shared__ float sba[F];
    __shared__ float sbb[F];
    for (int i = threadIdx.x; i < F * F; i += blockDim.x) {
        sWa[i] = W1a[i];
        sWb[i] = W1b[i];
    }
    if (threadIdx.x < F) {
        sba[threadIdx.x] = b1a[threadIdx.x];
        sbb[threadIdx.x] = b1b[threadIdx.x];
    }
    __syncthreads();
    int wave = threadIdx.x >> 6;
    int lane = threadIdx.x & 63;
    int nwaves = (blockDim.x >> 6) * gridDim.x;
    for (int row = blockIdx.x * (blockDim.x >> 6) + wave; row < n; row += nwaves) {
        size_t base = (size_t)row * F;
        float h = x_task[base + lane] + agg[base + lane];
        float acc = sba[lane];
        #pragma unroll
        for (int k = 0; k < F; ++k) {
            float hk = __shfl(h, k);
            acc += hk * sWa[k * F + lane];
        }
        float hid = fmaxf(acc, 0.f);
        float acc2 = sbb[lane];
        #pragma unroll
        for (int k = 0; k < F; ++k) {
            float hk = __shfl(hid, k);
            acc2 += hk * sWb[k * F + lane];
        }
        x1[base + lane] = acc2;
    }
}

// ---------------- edge2: GINConv scatter-add ---------------------------
__global__ __launch_bounds__(256) void edge2_kernel(
    const float* __restrict__ x1,
    const int* __restrict__ src,
    const int* __restrict__ dst,
    float* __restrict__ agg2,
    int E)
{
    long long t = (long long)blockIdx.x * blockDim.x + threadIdx.x;
    int e = (int)(t >> 4);
    int q = (int)(t & 15);
    if (e >= E) return;
    int s = src[e];
    int d = dst[e];
    float4 v = ((const float4* __restrict__)(x1 + (size_t)s * F))[q];
    float* ap = agg2 + (size_t)d * F + q * 4;
    atomicAdd(ap + 0, v.x);
    atomicAdd(ap + 1, v.y);
    atomicAdd(ap + 2, v.z);
    atomicAdd(ap + 3, v.w);
}

// ---------------- mlp2: out = relu((x_actor+agg2)@W2a+b2a)@W2b + b2b ---
__global__ __launch_bounds__(256) void mlp2_kernel(
    const float* __restrict__ x_actor,
    const float* __restrict__ agg2,
    const float* __restrict__ W2a, const float* __restrict__ b2a,
    const float* __restrict__ W2b, const float* __restrict__ b2b,
    float* __restrict__ out,
    int n)
{
    __shared__ float sWa[F * F];
    __shared__ float sba[F];
    __shared__ float sWb[F];
    for (int i = threadIdx.x; i < F * F; i += blockDim.x) sWa[i] = W2a[i];
    if (threadIdx.x < F) {
        sba[threadIdx.x] = b2a[threadIdx.x];
        sWb[threadIdx.x] = W2b[threadIdx.x];
    }
    __syncthreads();
    int wave = threadIdx.x >> 6;
    int lane = threadIdx.x & 63;
    int nwaves = (blockDim.x >> 6) * gridDim.x;
    float bias2 = b2b[0];
    for (int row = blockIdx.x * (blockDim.x >> 6) + wave; row < n; row += nwaves) {
        size_t base = (size_t)row * F;
        float h = x_actor[base + lane] + agg2[base + lane];
        float acc = sba[lane];
        #pragma unroll
        for (int k = 0; k < F; ++k) {
            float hk = __shfl(h, k);
            acc += hk * sWa[k * F + lane];
        }
        float p = fmaxf(acc, 0.f) * sWb[lane];
        // wave64 reduction
        #pragma unroll
        for (int off = 32; off > 0; off >>= 1)
            p += __shfl_down(p, off);
        if (lane == 0) out[row] = p + bias2;
    }
}

extern "C" void kernel_launch(void* const* d_in, const int* in_sizes, int n_in,
                              void* d_out, int out_size, void* d_ws, size_t ws_size,
                              hipStream_t stream)
{
    const float* x_state   = (const float*)d_in[0];
    const float* x_task    = (const float*)d_in[1];
    const float* x_actor   = (const float*)d_in[2];
    const float* edge_attr = (const float*)d_in[3];
    const float* We        = (const float*)d_in[4];
    const float* be        = (const float*)d_in[5];
    const float* W1a       = (const float*)d_in[6];
    const float* b1a       = (const float*)d_in[7];
    const float* W1b       = (const float*)d_in[8];
    const float* b1b       = (const float*)d_in[9];
    const float* W2a       = (const float*)d_in[10];
    const float* b2a       = (const float*)d_in[11];
    const float* W2b       = (const float*)d_in[12];
    const float* b2b       = (const float*)d_in[13];
    const int*   src_st    = (const int*)d_in[14];
    const int*   dst_st    = (const int*)d_in[15];
    const int*   src_ta    = (const int*)d_in[16];
    const int*   dst_ta    = (const int*)d_in[17];

    int n_task  = in_sizes[1] / F;
    int n_actor = in_sizes[2] / F;
    int E_st    = in_sizes[14];
    int E_ta    = in_sizes[16];

    float* agg  = (float*)d_ws;                       // [n_task, F]
    float* x1   = agg  + (size_t)n_task * F;          // [n_task, F]
    float* agg2 = x1   + (size_t)n_task * F;          // [n_actor, F]

    hipMemsetAsync(agg,  0, (size_t)n_task  * F * sizeof(float), stream);
    hipMemsetAsync(agg2, 0, (size_t)n_actor * F * sizeof(float), stream);

    {
        long long threads = (long long)E_st * 16;
        int blocks = (int)((threads + 255) / 256);
        edge1_kernel<<<blocks, 256, 0, stream>>>(x_state, edge_attr, We, be,
                                                 src_st, dst_st, agg, E_st);
    }
    mlp1_kernel<<<2048, 256, 0, stream>>>(x_task, agg, W1a, b1a, W1b, b1b, x1, n_task);
    {
        long long threads = (long long)E_ta * 16;
        int blocks = (int)((threads + 255) / 256);
        edge2_kernel<<<blocks, 256, 0, stream>>>(x1, src_ta, dst_ta, agg2, E_ta);
    }
    mlp2_kernel<<<2048, 256, 0, stream>>>(x_actor, agg2, W2a, b2a, W2b, b2b,
                                          (float*)d_out, n_actor);
}

// Round 2
// 916.027 us; speedup vs baseline: 2.9977x; 2.9977x over previous
//
#include <hip/hip_runtime.h>

#define F 64

// ======================= counting-sort helpers =======================

__global__ __launch_bounds__(256) void hist_kernel(
    const int* __restrict__ dst, int* __restrict__ counts, int E)
{
    int e = blockIdx.x * blockDim.x + threadIdx.x;
    if (e >= E) return;
    atomicAdd(&counts[dst[e]], 1);
}

// single-block exclusive scan over nbins (nbins <= 1024*32)
__global__ __launch_bounds__(1024) void scan_kernel(
    const int* __restrict__ counts, int* __restrict__ offsets,
    int* __restrict__ cursor, int nbins)
{
    __shared__ int lds[1024];
    int t = threadIdx.x;
    int per = (nbins + 1023) / 1024;
    int base_i = t * per;
    int local[64];  // per <= 64 supported
    int sum = 0;
    for (int j = 0; j < per; ++j) {
        int idx = base_i + j;
        local[j] = sum;
        sum += (idx < nbins) ? counts[idx] : 0;
    }
    lds[t] = sum;
    __syncthreads();
    // inclusive Hillis-Steele scan
    for (int off = 1; off < 1024; off <<= 1) {
        int v = (t >= off) ? lds[t - off] : 0;
        __syncthreads();
        lds[t] += v;
        __syncthreads();
    }
    int base = (t == 0) ? 0 : lds[t - 1];
    for (int j = 0; j < per; ++j) {
        int idx = base_i + j;
        if (idx < nbins) {
            int o = base + local[j];
            offsets[idx] = o;
            cursor[idx] = o;
        }
    }
}

__global__ __launch_bounds__(256) void scatter_kernel(
    const int* __restrict__ dst, int* __restrict__ cursor,
    int* __restrict__ perm, int E)
{
    int e = blockIdx.x * blockDim.x + threadIdx.x;
    if (e >= E) return;
    int pos = atomicAdd(&cursor[dst[e]], 1);
    perm[pos] = e;
}

// ============== gather1: agg[d] = sum_e relu(x_state[src[e]] + ea@We + be) ==============
// one wave per dst row; 16 lanes per edge (float4), 4 edges in flight per wave.
__global__ __launch_bounds__(256) void gather1_kernel(
    const float* __restrict__ x_state,
    const float* __restrict__ edge_attr,
    const float* __restrict__ We,   // [2][F]
    const float* __restrict__ be,
    const int* __restrict__ src,
    const int* __restrict__ perm,
    const int* __restrict__ offsets,
    const int* __restrict__ counts,
    float* __restrict__ agg,
    int n)
{
    int wave = threadIdx.x >> 6;
    int lane = threadIdx.x & 63;
    int d = blockIdx.x * 4 + wave;
    if (d >= n) return;
    int q = lane & 15;
    int g = lane >> 4;
    float4 w0 = ((const float4* __restrict__)We)[q];
    float4 w1 = ((const float4* __restrict__)(We + F))[q];
    float4 bb = ((const float4* __restrict__)be)[q];
    int start = offsets[d];
    int cnt = counts[d];
    float4 acc = make_float4(0.f, 0.f, 0.f, 0.f);
    for (int it = 0; it * 4 + g < cnt; ++it) {
        int idx = it * 4 + g;
        int e = perm[start + idx];
        int s = src[e];
        float2 ea = ((const float2* __restrict__)edge_attr)[e];
        float4 xs = ((const float4* __restrict__)x_state)[(size_t)s * 16 + q];
        acc.x += fmaxf(xs.x + ea.x * w0.x + ea.y * w1.x + bb.x, 0.f);
        acc.y += fmaxf(xs.y + ea.x * w0.y + ea.y * w1.y + bb.y, 0.f);
        acc.z += fmaxf(xs.z + ea.x * w0.z + ea.y * w1.z + bb.z, 0.f);
        acc.w += fmaxf(xs.w + ea.x * w0.w + ea.y * w1.w + bb.w, 0.f);
    }
    // reduce across the 4 groups (lanes q, q+16, q+32, q+48)
    acc.x += __shfl_xor(acc.x, 32); acc.y += __shfl_xor(acc.y, 32);
    acc.z += __shfl_xor(acc.z, 32); acc.w += __shfl_xor(acc.w, 32);
    acc.x += __shfl_xor(acc.x, 16); acc.y += __shfl_xor(acc.y, 16);
    acc.z += __shfl_xor(acc.z, 16); acc.w += __shfl_xor(acc.w, 16);
    if (g == 0)
        ((float4* __restrict__)agg)[(size_t)d * 16 + q] = acc;
}

// ============== gather2: agg2[d] = sum_e x1[src[e]] ==============
__global__ __launch_bounds__(256) void gather2_kernel(
    const float* __restrict__ x1,
    const int* __restrict__ src,
    const int* __restrict__ perm,
    const int* __restrict__ offsets,
    const int* __restrict__ counts,
    float* __restrict__ agg2,
    int n)
{
    int wave = threadIdx.x >> 6;
    int lane = threadIdx.x & 63;
    int d = blockIdx.x * 4 + wave;
    if (d >= n) return;
    int q = lane & 15;
    int g = lane >> 4;
    int start = offsets[d];
    int cnt = counts[d];
    float4 acc = make_float4(0.f, 0.f, 0.f, 0.f);
    for (int it = 0; it * 4 + g < cnt; ++it) {
        int idx = it * 4 + g;
        int e = perm[start + idx];
        int s = src[e];
        float4 v = ((const float4* __restrict__)x1)[(size_t)s * 16 + q];
        acc.x += v.x; acc.y += v.y; acc.z += v.z; acc.w += v.w;
    }
    acc.x += __shfl_xor(acc.x, 32); acc.y += __shfl_xor(acc.y, 32);
    acc.z += __shfl_xor(acc.z, 32); acc.w += __shfl_xor(acc.w, 32);
    acc.x += __shfl_xor(acc.x, 16); acc.y += __shfl_xor(acc.y, 16);
    acc.z += __shfl_xor(acc.z, 16); acc.w += __shfl_xor(acc.w, 16);
    if (g == 0)
        ((float4* __restrict__)agg2)[(size_t)d * 16 + q] = acc;
}

// ---------------- mlp1: x1 = relu((x_task+agg)@W1a+b1a)@W1b + b1b ------
__global__ __launch_bounds__(256) void mlp1_kernel(
    const float* __restrict__ x_task,
    const float* __restrict__ agg,
    const float* __restrict__ W1a, const float* __restrict__ b1a,
    const float* __restrict__ W1b, const float* __restrict__ b1b,
    float* __restrict__ x1,
    int n)
{
    __shared__ float sWa[F * F];
    __shared__ float sWb[F * F];
    __shared__ float sba[F];
    __shared__ float sbb[F];
    for (int i = threadIdx.x; i < F * F; i += blockDim.x) {
        sWa[i] = W1a[i];
        sWb[i] = W1b[i];
    }
    if (threadIdx.x < F) {
        sba[threadIdx.x] = b1a[threadIdx.x];
        sbb[threadIdx.x] = b1b[threadIdx.x];
    }
    __syncthreads();
    int wave = threadIdx.x >> 6;
    int lane = threadIdx.x & 63;
    int nwaves = (blockDim.x >> 6) * gridDim.x;
    for (int row = blockIdx.x * (blockDim.x >> 6) + wave; row < n; row += nwaves) {
        size_t base = (size_t)row * F;
        float h = x_task[base + lane] + agg[base + lane];
        float acc = sba[lane];
        #pragma unroll
        for (int k = 0; k < F; ++k) {
            float hk = __shfl(h, k);
            acc += hk * sWa[k * F + lane];
        }
        float hid = fmaxf(acc, 0.f);
        float acc2 = sbb[lane];
        #pragma unroll
        for (int k = 0; k < F; ++k) {
            float hk = __shfl(hid, k);
            acc2 += hk * sWb[k * F + lane];
        }
        x1[base + lane] = acc2;
    }
}

// ---------------- mlp2: out = relu((x_actor+agg2)@W2a+b2a)@W2b + b2b ---
__global__ __launch_bounds__(256) void mlp2_kernel(
    const float* __restrict__ x_actor,
    const float* __restrict__ agg2,
    const float* __restrict__ W2a, const float* __restrict__ b2a,
    const float* __restrict__ W2b, const float* __restrict__ b2b,
    float* __restrict__ out,
    int n)
{
    __shared__ float sWa[F * F];
    __shared__ float sba[F];
    __shared__ float sWb[F];
    for (int i = threadIdx.x; i < F * F; i += blockDim.x) sWa[i] = W2a[i];
    if (threadIdx.x < F) {
        sba[threadIdx.x] = b2a[threadIdx.x];
        sWb[threadIdx.x] = W2b[threadIdx.x];
    }
    __syncthreads();
    int wave = threadIdx.x >> 6;
    int lane = threadIdx.x & 63;
    int nwaves = (blockDim.x >> 6) * gridDim.x;
    float bias2 = b2b[0];
    for (int row = blockIdx.x * (blockDim.x >> 6) + wave; row < n; row += nwaves) {
        size_t base = (size_t)row * F;
        float h = x_actor[base + lane] + agg2[base + lane];
        float acc = sba[lane];
        #pragma unroll
        for (int k = 0; k < F; ++k) {
            float hk = __shfl(h, k);
            acc += hk * sWa[k * F + lane];
        }
        float p = fmaxf(acc, 0.f) * sWb[lane];
        #pragma unroll
        for (int off = 32; off > 0; off >>= 1)
            p += __shfl_down(p, off);
        if (lane == 0) out[row] = p + bias2;
    }
}

extern "C" void kernel_launch(void* const* d_in, const int* in_sizes, int n_in,
                              void* d_out, int out_size, void* d_ws, size_t ws_size,
                              hipStream_t stream)
{
    const float* x_state   = (const float*)d_in[0];
    const float* x_task    = (const float*)d_in[1];
    const float* x_actor   = (const float*)d_in[2];
    const float* edge_attr = (const float*)d_in[3];
    const float* We        = (const float*)d_in[4];
    const float* be        = (const float*)d_in[5];
    const float* W1a       = (const float*)d_in[6];
    const float* b1a       = (const float*)d_in[7];
    const float* W1b       = (const float*)d_in[8];
    const float* b1b       = (const float*)d_in[9];
    const float* W2a       = (const float*)d_in[10];
    const float* b2a       = (const float*)d_in[11];
    const float* W2b       = (const float*)d_in[12];
    const float* b2b       = (const float*)d_in[13];
    const int*   src_st    = (const int*)d_in[14];
    const int*   dst_st    = (const int*)d_in[15];
    const int*   src_ta    = (const int*)d_in[16];
    const int*   dst_ta    = (const int*)d_in[17];

    int n_task  = in_sizes[1] / F;
    int n_actor = in_sizes[2] / F;
    int E_st    = in_sizes[14];
    int E_ta    = in_sizes[16];

    // ---- workspace layout (4-byte units) ----
    float* agg     = (float*)d_ws;                         // [n_task*F]   8 MB
    float* x1      = agg  + (size_t)n_task * F;            // [n_task*F]   8 MB
    float* agg2    = x1   + (size_t)n_task * F;            // [n_actor*F]  8 MB
    int*   counts  = (int*)(agg2 + (size_t)n_actor * F);   // [32768]
    int*   offsets = counts + 32768;                       // [32768]
    int*   cursor  = offsets + 32768;                      // [32768]
    int*   perm    = cursor + 32768;                       // [E_st] (reused for E_ta)

    // ======== stage 1: GINEConv via counting sort + gather ========
    hipMemsetAsync(counts, 0, 32768 * sizeof(int), stream);
    hist_kernel<<<(E_st + 255) / 256, 256, 0, stream>>>(dst_st, counts, E_st);
    scan_kernel<<<1, 1024, 0, stream>>>(counts, offsets, cursor, n_task);
    scatter_kernel<<<(E_st + 255) / 256, 256, 0, stream>>>(dst_st, cursor, perm, E_st);
    gather1_kernel<<<(n_task + 3) / 4, 256, 0, stream>>>(
        x_state, edge_attr, We, be, src_st, perm, offsets, counts, agg, n_task);

    mlp1_kernel<<<2048, 256, 0, stream>>>(x_task, agg, W1a, b1a, W1b, b1b, x1, n_task);

    // ======== stage 2: GINConv via counting sort + gather ========
    hipMemsetAsync(counts, 0, 32768 * sizeof(int), stream);
    hist_kernel<<<(E_ta + 255) / 256, 256, 0, stream>>>(dst_ta, counts, E_ta);
    scan_kernel<<<1, 1024, 0, stream>>>(counts, offsets, cursor, n_actor);
    scatter_kernel<<<(E_ta + 255) / 256, 256, 0, stream>>>(dst_ta, cursor, perm, E_ta);
    gather2_kernel<<<(n_actor + 3) / 4, 256, 0, stream>>>(
        x1, src_ta, perm, offsets, counts, agg2, n_actor);

    mlp2_kernel<<<2048, 256, 0, stream>>>(x_actor, agg2, W2a, b2a, W2b, b2b,
                                          (float*)d_out, n_actor);
}